// Round 4
// baseline (386.465 us; speedup 1.0000x reference)
//
#include <hip/hip_runtime.h>
#include <hip/hip_fp16.h>

#define SEQ 8192
#define DIM 1024
#define NN  4096
#define NT  32                    // K-tiles of 64 over KEFF=2048 ([x_hi | x_lo])

using f16x8 = __attribute__((ext_vector_type(8))) _Float16;
using f32x4 = __attribute__((ext_vector_type(4))) float;

__device__ __forceinline__ float fast_tanh(float x) {
    float e = __expf(2.0f * x);
    return 1.0f - 2.0f / (e + 1.0f);
}

// ---------------------------------------------------------------------------
// Single fused kernel. 256x256 tile, BK=64 (effective K = 2048 = [hi|lo] of
// DIM=1024), 8 waves (2M x 4N), 128 KiB LDS dbuf, 4 phases/KT with 2 barriers
// each (m201 pattern). Staging is REG-STAGED straight from fp32 x/W:
//   P1: issue A(t+1) float4 loads          | read aH0,bN01 frags | MFMA q00
//   P2: cvt+ds_write A(t+1) -> buf dn      | read bN23           | MFMA q01
//   P3: issue B(t+1) float4 loads          | read aH1            | MFMA q10
//   P4: cvt+ds_write B(t+1) -> buf dn      |                     | MFMA q11
// KT t>=16 stages lo(x) instead of hi(x); B wraps (kt&15) and is always hi(W).
// Race-freedom: all iter-t reads hit buf d, all writes hit buf dn; writes
// complete (lgkmcnt(0)) before their phase's first barrier; first reader of
// dn is iter t+1 P1, >=3 barriers later. No global_load_lds -> no vmcnt
// choreography; f32 loads stay in flight across barriers, compiler inserts
// per-value vmcnt before the cvt that consumes them (1-phase latency cover).
// Swizzle: LDS granule p of row r holds global granule p ^ (r&7); staging
// thread (srow=tid>>3, p=tid&7) loads global granule (tid&7)^(srow&7) and
// writes tid-linear (16B * tid) -> wave writes 1KB contiguous, conflict-free.
// Frag reads use granule ^ (l15&7) -- unchanged from the verified kernel.
__global__ __launch_bounds__(512, 2) void gemm_tanh_kernel(
        const float* __restrict__ x,      // [SEQ][DIM] fp32
        const float* __restrict__ w,      // [NN][DIM] fp32
        const float* __restrict__ bias,   // [NN]
        float* __restrict__ out) {        // [SEQ][NN] fp32
    __shared__ _Float16 lds[65536];       // 128 KB: (A 32K | B 32K) x 2 bufs

    const int tid  = threadIdx.x;
    const int lane = tid & 63;
    const int wave = tid >> 6;            // 0..7
    const int wm   = wave >> 2;           // 0..1 (M)
    const int wn   = wave & 3;            // 0..3 (N)
    const int l15  = lane & 15;
    const int lq   = lane >> 4;           // 0..3

    // XCD map: xcd owns pb in [4*xcd, 4*xcd+4); concurrent batch = 4pb x 8qb.
    const int xcd = blockIdx.x & 7;
    const int idx = blockIdx.x >> 3;      // 0..63
    const int pb  = xcd * 4 + (idx & 3);  // 0..31
    const int qb  = idx >> 2;             // 0..15
    const int rowBase = pb << 8;
    const int colBase = qb << 8;

    // swizzled ds_read offsets (unchanged, verified)
    const int sw  = l15 & 7;
    const int gk0 = ((lq)     ^ sw) << 4;
    const int gk1 = ((4 + lq) ^ sw) << 4;
    const int aOff = wm * 2048 + l15 * 128;
    const int bOff = 32768 + wn * 2048 + l15 * 128;

    // staging thread map
    const int srow = tid >> 3;            // 0..63
    const int sg   = (tid & 7) ^ (srow & 7);
    const int scol = sg * 8;              // f32 col within the 64-col tile

    char* ldsc = (char*)lds;
    char* wb   = ldsc + tid * 16;         // staging write base (tid-linear)
    const float* xRow = x + (size_t)(rowBase + srow) * DIM + scol;
    const float* wRow = w + (size_t)(colBase + srow) * DIM + scol;

    f32x4 acc[8][4] = {};
    float4 stg[8];                        // shared between A and B staging
    f16x8 aH[4][2], bN01[2][2], bN23[2][2];

    auto loadStageA = [&](int s) {
        const int rk = (s & 15) << 6;
#pragma unroll
        for (int c = 0; c < 4; ++c) {     // c = h*2 + rowhalf -> rows c*64+srow
            const float* p = xRow + (size_t)(c * 64) * DIM + rk;
            stg[2 * c]     = *(const float4*)p;
            stg[2 * c + 1] = *(const float4*)(p + 4);
        }
    };
    auto loadStageB = [&](int s) {
        const int rk = (s & 15) << 6;
#pragma unroll
        for (int c = 0; c < 4; ++c) {
            const float* p = wRow + (size_t)(c * 64) * DIM + rk;
            stg[2 * c]     = *(const float4*)p;
            stg[2 * c + 1] = *(const float4*)(p + 4);
        }
    };
    auto writeStageA = [&](int s, int db) {
        char* d0 = wb + db * 65536;
        const bool lo = (s >> 4) != 0;    // KT >= 16: lo(x)
#pragma unroll
        for (int c = 0; c < 4; ++c) {
            const float f[8] = {stg[2*c].x, stg[2*c].y, stg[2*c].z, stg[2*c].w,
                                stg[2*c+1].x, stg[2*c+1].y, stg[2*c+1].z, stg[2*c+1].w};
            f16x8 hv;
            if (lo) {
#pragma unroll
                for (int e = 0; e < 8; ++e) {
                    const _Float16 h = (_Float16)f[e];
                    hv[e] = (_Float16)(f[e] - (float)h);
                }
            } else {
#pragma unroll
                for (int e = 0; e < 8; ++e) hv[e] = (_Float16)f[e];
            }
            *(f16x8*)(d0 + c * 8192) = hv;   // h*16384 + rowhalf*8192 = c*8192
        }
    };
    auto writeStageB = [&](int db) {
        char* d0 = wb + db * 65536 + 32768;
#pragma unroll
        for (int c = 0; c < 4; ++c) {
            const float f[8] = {stg[2*c].x, stg[2*c].y, stg[2*c].z, stg[2*c].w,
                                stg[2*c+1].x, stg[2*c+1].y, stg[2*c+1].z, stg[2*c+1].w};
            f16x8 hv;
#pragma unroll
            for (int e = 0; e < 8; ++e) hv[e] = (_Float16)f[e];
            *(f16x8*)(d0 + c * 8192) = hv;
        }
    };

    // Prologue: stage KT0 -> buf0.
    loadStageA(0); writeStageA(0, 0);
    loadStageB(0); writeStageB(0);
    asm volatile("s_waitcnt lgkmcnt(0)" ::: "memory");
    __builtin_amdgcn_sched_barrier(0);
    __builtin_amdgcn_s_barrier();

    for (int t = 0; t < NT; ++t) {
        const int d  = t & 1;
        const int dn = d ^ 1;
        const char* lb = ldsc + d * 65536;

        // ---- P1: issue A(t+1); read aH0,bN01; MFMA (mh0 x n01)
        if (t + 1 < NT) loadStageA(t + 1);
#pragma unroll
        for (int i = 0; i < 4; ++i) {
            aH[i][0] = *(const f16x8*)(lb + aOff + i * 4096 + gk0);
            aH[i][1] = *(const f16x8*)(lb + aOff + i * 4096 + gk1);
        }
#pragma unroll
        for (int j = 0; j < 2; ++j) {
            bN01[j][0] = *(const f16x8*)(lb + bOff + j * 8192 + gk0);
            bN01[j][1] = *(const f16x8*)(lb + bOff + j * 8192 + gk1);
        }
        asm volatile("s_waitcnt lgkmcnt(0)" ::: "memory");
        __builtin_amdgcn_sched_barrier(0);
        __builtin_amdgcn_s_barrier();
        __builtin_amdgcn_s_setprio(1);
#pragma unroll
        for (int k = 0; k < 2; ++k)
#pragma unroll
            for (int i = 0; i < 4; ++i)
#pragma unroll
                for (int j = 0; j < 2; ++j)
                    acc[i][j] = __builtin_amdgcn_mfma_f32_16x16x32_f16(
                        aH[i][k], bN01[j][k], acc[i][j], 0, 0, 0);
        __builtin_amdgcn_s_setprio(0);
        __builtin_amdgcn_s_barrier();

        // ---- P2: write A(t+1) -> dn; read bN23; MFMA (mh0 x n23)
        if (t + 1 < NT) writeStageA(t + 1, dn);
#pragma unroll
        for (int j = 0; j < 2; ++j) {
            bN23[j][0] = *(const f16x8*)(lb + bOff + 16384 + j * 8192 + gk0);
            bN23[j][1] = *(const f16x8*)(lb + bOff + 16384 + j * 8192 + gk1);
        }
        asm volatile("s_waitcnt lgkmcnt(0)" ::: "memory");
        __builtin_amdgcn_sched_barrier(0);
        __builtin_amdgcn_s_barrier();
        __builtin_amdgcn_s_setprio(1);
#pragma unroll
        for (int k = 0; k < 2; ++k)
#pragma unroll
            for (int i = 0; i < 4; ++i)
#pragma unroll
                for (int j = 0; j < 2; ++j)
                    acc[i][2 + j] = __builtin_amdgcn_mfma_f32_16x16x32_f16(
                        aH[i][k], bN23[j][k], acc[i][2 + j], 0, 0, 0);
        __builtin_amdgcn_s_setprio(0);
        __builtin_amdgcn_s_barrier();

        // ---- P3: issue B(t+1); read aH1; MFMA (mh1 x n01)
        if (t + 1 < NT) loadStageB(t + 1);
#pragma unroll
        for (int i = 0; i < 4; ++i) {
            aH[i][0] = *(const f16x8*)(lb + aOff + 16384 + i * 4096 + gk0);
            aH[i][1] = *(const f16x8*)(lb + aOff + 16384 + i * 4096 + gk1);
        }
        asm volatile("s_waitcnt lgkmcnt(0)" ::: "memory");
        __builtin_amdgcn_sched_barrier(0);
        __builtin_amdgcn_s_barrier();
        __builtin_amdgcn_s_setprio(1);
#pragma unroll
        for (int k = 0; k < 2; ++k)
#pragma unroll
            for (int i = 0; i < 4; ++i)
#pragma unroll
                for (int j = 0; j < 2; ++j)
                    acc[4 + i][j] = __builtin_amdgcn_mfma_f32_16x16x32_f16(
                        aH[i][k], bN01[j][k], acc[4 + i][j], 0, 0, 0);
        __builtin_amdgcn_s_setprio(0);
        __builtin_amdgcn_s_barrier();

        // ---- P4: write B(t+1) -> dn; MFMA (mh1 x n23)
        if (t + 1 < NT) writeStageB(dn);
        asm volatile("s_waitcnt lgkmcnt(0)" ::: "memory");
        __builtin_amdgcn_sched_barrier(0);
        __builtin_amdgcn_s_barrier();
        __builtin_amdgcn_s_setprio(1);
#pragma unroll
        for (int k = 0; k < 2; ++k)
#pragma unroll
            for (int i = 0; i < 4; ++i)
#pragma unroll
                for (int j = 0; j < 2; ++j)
                    acc[4 + i][2 + j] = __builtin_amdgcn_mfma_f32_16x16x32_f16(
                        aH[i][k], bN23[j][k], acc[4 + i][2 + j], 0, 0, 0);
        __builtin_amdgcn_s_setprio(0);
        __builtin_amdgcn_s_barrier();
    }

    // Epilogue: C/D col = lane&15, row = (lane>>4)*4 + reg. Wave rows are
    // 16-interleaved: row(r) = rowBase + (r*2+wm)*16; col(j) = (j*4+wn)*16.
#pragma unroll
    for (int j = 0; j < 4; ++j) {
        const int col = colBase + (j * 4 + wn) * 16 + l15;
        const float bj = bias[col];
#pragma unroll
        for (int r = 0; r < 8; ++r) {
            const size_t rb = (size_t)(rowBase + (r * 2 + wm) * 16 + lq * 4) * NN + col;
#pragma unroll
            for (int v = 0; v < 4; ++v)
                out[rb + (size_t)v * NN] = fast_tanh(acc[r][j][v] + bj);
        }
    }
}

// ---------------------------------------------------------------------------
extern "C" void kernel_launch(void* const* d_in, const int* in_sizes, int n_in,
                              void* d_out, int out_size, void* d_ws, size_t ws_size,
                              hipStream_t stream) {
    const float* x = (const float*)d_in[0];
    const float* W = (const float*)d_in[1];
    const float* b = (const float*)d_in[2];
    float* out = (float*)d_out;
    (void)d_ws; (void)ws_size;

    gemm_tanh_kernel<<<512, 512, 0, stream>>>(x, W, b, out);
}

// Round 5
// 302.696 us; speedup vs baseline: 1.2767x; 1.2767x over previous
//
#include <hip/hip_runtime.h>
#include <hip/hip_fp16.h>

#define SEQ 8192
#define DIM 1024
#define NN  4096
#define KEFF 2048                 // [x_hi | x_lo] along K
#define NKT 64                    // K-tiles of 32 over KEFF
#define A_BYTES ((size_t)SEQ * KEFF * 2)   // 33.55 MB fp16
#define B_BYTES ((size_t)NN * DIM * 2)     //  8.39 MB fp16 (W_hi, consumed twice)

using f16x8 = __attribute__((ext_vector_type(8))) _Float16;
using f16x4 = __attribute__((ext_vector_type(4))) _Float16;
using f32x4 = __attribute__((ext_vector_type(4))) float;

typedef __attribute__((address_space(1))) unsigned char as1_u8;
typedef __attribute__((address_space(3))) unsigned char as3_u8;

__device__ __forceinline__ float fast_tanh(float x) {
    float e = __expf(2.0f * x);
    return 1.0f - 2.0f / (e + 1.0f);
}

// ---------------------------------------------------------------------------
// Convert (verified in R2): one float4 per thread, unit-stride.
// A[s][k]=hi(x[s][k]), A[s][k+1024]=lo. B[n][k]=hi(W[n][k]).
__global__ __launch_bounds__(256) void convert_kernel(
        const float* __restrict__ x, const float* __restrict__ w,
        f16x4* __restrict__ A, f16x4* __restrict__ B) {
    const int tid = threadIdx.x;
    const int b   = blockIdx.x;
    if (b < 8192) {
        const int gid = b * 256 + tid;
        const int s   = gid >> 8;
        const int c   = gid & 255;
        const float4 v = ((const float4*)x)[(size_t)s * 256 + c];
        const float f[4] = {v.x, v.y, v.z, v.w};
        f16x4 hv, lv;
#pragma unroll
        for (int e = 0; e < 4; e++) {
            const _Float16 h = (_Float16)f[e];
            hv[e] = h;
            lv[e] = (_Float16)(f[e] - (float)h);
        }
        f16x4* dst = A + (size_t)s * 512 + c;
        dst[0]   = hv;
        dst[256] = lv;
    } else {
        const int gid = (b - 8192) * 256 + tid;
        const int n   = gid >> 8;
        const int c   = gid & 255;
        const float4 v = ((const float4*)w)[(size_t)n * 256 + c];
        const float f[4] = {v.x, v.y, v.z, v.w};
        f16x4 hv;
#pragma unroll
        for (int e = 0; e < 4; e++) hv[e] = (_Float16)f[e];
        B[(size_t)n * 256 + c] = hv;
    }
}

// ---------------------------------------------------------------------------
// GEMM: block 256x128, 4 waves (2m x 2n, wave tile 128x64), BK=32, TRIPLE-
// buffered LDS (3 x 24 KB = 72 KB) -> 2 independent blocks per CU (144 KB).
// While one block drains its LDS-read window the other occupies the MFMA
// pipes -- removes the single-barrier-group serialization that pinned all
// previous structures at 151 us. One barrier per K-tile; counted vmcnt(6)
// (stage distance 2 via tri-buffer, never drained to 0 in the loop).
// Race-audit: stage(t+2) -> buf (t+2)%3, last read at iter t-1, retired
// before the t-1 end-barrier that every wave passed before iter t began.
// Buf cur readiness: vmcnt(6) at end of t-1 leaves only KT(t+1)'s 6 loads
// outstanding => KT(t)'s staging landed; barrier publishes it.
// Layouts: buf = A[256 rows][32 f16] (16 KB) | B[128 rows][32 f16] (8 KB),
// 64-B rows, 16-B granules XOR-swizzled g' = g ^ (row&3); staging writes
// tid-linear (wave-uniform base + lane*16, gload_lds requirement) with the
// inverse swizzle applied to the per-lane GLOBAL source address.
__global__ __launch_bounds__(256, 2) void gemm_tanh_kernel(
        const _Float16* __restrict__ A,   // [SEQ][KEFF]
        const _Float16* __restrict__ B,   // [NN][DIM]
        const float* __restrict__ bias,   // [NN]
        float* __restrict__ out) {        // [SEQ][NN] fp32
    __shared__ _Float16 lds[36864];       // 72 KB: 3 x (A 16K | B 8K)

    const int tid  = threadIdx.x;
    const int lane = tid & 63;
    const int wave = tid >> 6;            // 0..3
    const int wm   = wave >> 1;           // 0..1 (m-half, 128 rows)
    const int wn   = wave & 1;            // 0..1 (n-half, 64 cols)
    const int l15  = lane & 15;
    const int lq   = lane >> 4;           // 0..3

    // XCD map: xcd owns qb in [4*xcd, 4*xcd+4) -> 1 MB B slice L2-resident.
    const int xcd = blockIdx.x & 7;
    const int idx = blockIdx.x >> 3;      // 0..127
    const int qb  = xcd * 4 + (idx & 3);  // 0..31 (128-col tiles)
    const int pb  = idx >> 2;             // 0..31 (256-row tiles)
    const int rowBase = pb << 8;
    const int colBase = qb << 7;

    // fragment-read offsets: row = blk*16 + l15, granule lq, swizzle r&3
    const int gsw = (lq ^ (l15 & 3)) << 4;
    const int aFr = wm * 8192 + l15 * 64 + gsw;          // + m*1024 + bufOff
    const int bFr = 16384 + wn * 4096 + l15 * 64 + gsw;  // + n*1024 + bufOff

    // staging map: issue-chunk = 64 rows; thread covers LDS off tid*16
    const int srA = tid >> 2;              // row within chunk (0..63)
    const int sgr = (tid & 3) ^ (srA & 3); // inverse-swizzled source granule
    char* ldsc = (char*)lds;

    const _Float16* Abase = A + (size_t)(rowBase + srA) * KEFF + sgr * 8;
    const _Float16* Bbase = B + (size_t)(colBase + srA) * DIM + sgr * 8;

    auto stageKT = [&](int kt, unsigned bufOff) {
        const _Float16* ga = Abase + kt * 32;
#pragma unroll
        for (int i = 0; i < 4; ++i)        // A: 4 x 64 rows
            __builtin_amdgcn_global_load_lds(
                (const as1_u8*)(ga + (size_t)i * 64 * KEFF),
                (as3_u8*)(ldsc + bufOff + i * 4096 + tid * 16), 16, 0, 0);
        const _Float16* gb = Bbase + (kt & 31) * 32;   // B repeats (hi only)
#pragma unroll
        for (int i = 0; i < 2; ++i)        // B: 2 x 64 rows
            __builtin_amdgcn_global_load_lds(
                (const as1_u8*)(gb + (size_t)i * 64 * DIM),
                (as3_u8*)(ldsc + bufOff + 16384 + i * 4096 + tid * 16), 16, 0, 0);
    };

    f32x4 acc[8][4] = {};
    f16x8 aF[8], bF[4];

    unsigned o0 = 0, o1 = 24576, o2 = 49152;   // rotating buffer offsets

    stageKT(0, o0);
    stageKT(1, o1);
    asm volatile("s_waitcnt vmcnt(6)" ::: "memory");   // KT0 landed
    __builtin_amdgcn_s_barrier();

    for (int t = 0; t < NKT; ++t) {
        const char* lb = ldsc + o0;
        // P1: frag reads (a m0-3, b n0-3); issue stage KT(t+2) -> o2
#pragma unroll
        for (int m = 0; m < 4; ++m) aF[m] = *(const f16x8*)(lb + aFr + m * 1024);
#pragma unroll
        for (int n = 0; n < 4; ++n) bF[n] = *(const f16x8*)(lb + bFr + n * 1024);
        if (t + 2 < NKT) stageKT(t + 2, o2);
        __builtin_amdgcn_s_setprio(1);
#pragma unroll
        for (int m = 0; m < 4; ++m)
#pragma unroll
            for (int n = 0; n < 4; ++n)
                acc[m][n] = __builtin_amdgcn_mfma_f32_16x16x32_f16(
                    aF[m], bF[n], acc[m][n], 0, 0, 0);
        __builtin_amdgcn_s_setprio(0);

        // P2: frag reads (a m4-7); MFMA second half
#pragma unroll
        for (int m = 0; m < 4; ++m) aF[4 + m] = *(const f16x8*)(lb + aFr + (4 + m) * 1024);
        __builtin_amdgcn_s_setprio(1);
#pragma unroll
        for (int m = 0; m < 4; ++m)
#pragma unroll
            for (int n = 0; n < 4; ++n)
                acc[4 + m][n] = __builtin_amdgcn_mfma_f32_16x16x32_f16(
                    aF[4 + m], bF[n], acc[4 + m][n], 0, 0, 0);
        __builtin_amdgcn_s_setprio(0);

        if (t + 2 < NKT) {
            asm volatile("s_waitcnt vmcnt(6)" ::: "memory");  // KT(t+1) landed
        } else if (t + 1 < NKT) {
            asm volatile("s_waitcnt vmcnt(0)" ::: "memory");  // tail drain
        }
        __builtin_amdgcn_s_barrier();
        const unsigned tmp = o0; o0 = o1; o1 = o2; o2 = tmp;
    }

    // Epilogue: C/D col = lane&15, row = (lane>>4)*4 + reg.
#pragma unroll
    for (int n = 0; n < 4; ++n) {
        const int col = colBase + wn * 64 + n * 16 + l15;
        const float bj = bias[col];
#pragma unroll
        for (int m = 0; m < 8; ++m) {
            const size_t rb = (size_t)(rowBase + wm * 128 + m * 16 + lq * 4) * NN + col;
#pragma unroll
            for (int v = 0; v < 4; ++v)
                out[rb + (size_t)v * NN] = fast_tanh(acc[m][n][v] + bj);
        }
    }
}

// ---------------------------------------------------------------------------
// Fallback (only if workspace too small): naive fp32 tiled GEMM.
__global__ void naive_gemm_kernel(const float* __restrict__ x,
                                  const float* __restrict__ W,
                                  const float* __restrict__ b,
                                  float* __restrict__ out) {
    __shared__ float xs[16][17], ws[16][17];
    int n = blockIdx.x * 16 + threadIdx.x;
    int m = blockIdx.y * 16 + threadIdx.y;
    float s = 0.f;
    for (int k0 = 0; k0 < DIM; k0 += 16) {
        xs[threadIdx.y][threadIdx.x] = x[(size_t)m * DIM + k0 + threadIdx.x];
        ws[threadIdx.y][threadIdx.x] =
            W[(size_t)(blockIdx.x * 16 + threadIdx.y) * DIM + k0 + threadIdx.x];
        __syncthreads();
#pragma unroll
        for (int kk = 0; kk < 16; kk++) s += xs[threadIdx.y][kk] * ws[threadIdx.x][kk];
        __syncthreads();
    }
    out[(size_t)m * NN + n] = tanhf(s + b[n]);
}

// ---------------------------------------------------------------------------
extern "C" void kernel_launch(void* const* d_in, const int* in_sizes, int n_in,
                              void* d_out, int out_size, void* d_ws, size_t ws_size,
                              hipStream_t stream) {
    const float* x = (const float*)d_in[0];
    const float* W = (const float*)d_in[1];
    const float* b = (const float*)d_in[2];
    float* out = (float*)d_out;

    const size_t need = A_BYTES + B_BYTES;   // 41.94 MB
    if (ws_size < need) {
        dim3 grid(NN / 16, SEQ / 16), block(16, 16);
        naive_gemm_kernel<<<grid, block, 0, stream>>>(x, W, b, out);
        return;
    }

    _Float16* Abuf = (_Float16*)d_ws;
    _Float16* Bbuf = Abuf + (size_t)SEQ * KEFF;

    convert_kernel<<<12288, 256, 0, stream>>>(x, W, (f16x4*)Abuf, (f16x4*)Bbuf);

    gemm_tanh_kernel<<<1024, 256, 0, stream>>>(Abuf, Bbuf, b, out);
}

// Round 6
// 280.177 us; speedup vs baseline: 1.3794x; 1.0804x over previous
//
#include <hip/hip_runtime.h>
#include <hip/hip_fp16.h>

#define SEQ 8192
#define DIM 1024
#define NN  4096
#define KEFF 2048                 // [x_hi | x_lo] along K
#define NT   32                   // K-tiles of 64 over KEFF
#define A_BYTES ((size_t)SEQ * KEFF * 2)   // 33.55 MB fp16
#define B_BYTES ((size_t)NN * DIM * 2)     //  8.39 MB fp16 (W_hi, consumed twice)

using f16x8 = __attribute__((ext_vector_type(8))) _Float16;
using f16x4 = __attribute__((ext_vector_type(4))) _Float16;
using f32x4 = __attribute__((ext_vector_type(4))) float;

typedef __attribute__((address_space(1))) unsigned char as1_u8;
typedef __attribute__((address_space(3))) unsigned char as3_u8;

__device__ __forceinline__ float fast_tanh(float x) {
    float e = __expf(2.0f * x);
    return 1.0f - 2.0f / (e + 1.0f);
}

// ---------------------------------------------------------------------------
// Convert (verified): one float4 per thread, unit-stride.
// A[s][k]=hi(x[s][k]), A[s][k+1024]=lo. B[n][k]=hi(W[n][k]).
__global__ __launch_bounds__(256) void convert_kernel(
        const float* __restrict__ x, const float* __restrict__ w,
        f16x4* __restrict__ A, f16x4* __restrict__ B) {
    const int tid = threadIdx.x;
    const int b   = blockIdx.x;
    if (b < 8192) {
        const int gid = b * 256 + tid;
        const int s   = gid >> 8;
        const int c   = gid & 255;
        const float4 v = ((const float4*)x)[(size_t)s * 256 + c];
        const float f[4] = {v.x, v.y, v.z, v.w};
        f16x4 hv, lv;
#pragma unroll
        for (int e = 0; e < 4; e++) {
            const _Float16 h = (_Float16)f[e];
            hv[e] = h;
            lv[e] = (_Float16)(f[e] - (float)h);
        }
        f16x4* dst = A + (size_t)s * 512 + c;
        dst[0]   = hv;
        dst[256] = lv;
    } else {
        const int gid = (b - 8192) * 256 + tid;
        const int n   = gid >> 8;
        const int c   = gid & 255;
        const float4 v = ((const float4*)w)[(size_t)n * 256 + c];
        const float f[4] = {v.x, v.y, v.z, v.w};
        f16x4 hv;
#pragma unroll
        for (int e = 0; e < 4; e++) hv[e] = (_Float16)f[e];
        B[(size_t)n * 256 + c] = hv;
    }
}

// ---------------------------------------------------------------------------
// GEMM: 256x256 tile, BK=64, 8 waves (2m x 4n, wave tile 128x64), 128 KiB
// LDS double-buffer, ONE barrier per K-tile (mid-iteration). Phases free-run:
// per iter t (reads buf d = KT t; stages KT(t+1) -> dn at top):
//   top : 8 x global_load_lds  KT(t+1) -> dn
//   q00 : MFMA(aH0 x bN01)   || ds_read bN23(d)
//   q01 : MFMA(aH0 x bN23)   || ds_read aH1(d)
//   mid : lgkmcnt(0) [own d-reads done]; vmcnt(0) [staging landed, issued
//         ~1200 cyc earlier]; s_barrier  -> publishes dn, certifies d free
//   q10 : MFMA(aH1 x bN01)   || ds_read aH0'(dn)   [KT(t+1) q00 frags]
//   q11 : MFMA(aH1 x bN23)   || ds_read bN01'(dn)
// No intra-iter barriers => waves skew; one wave's LDS-read window overlaps
// other waves' MFMA windows (the serialization that pinned R1/R2/R5 at 41%
// MfmaUtil). Race audit: every read of a buffer completes (lgkm-drained)
// before the mid-barrier that precedes that buffer's next staging; staging
// into dn is issued before mid-barrier but dn's prior readers all finished
// before the PREVIOUS mid-barrier. sched_barrier(0) pins ops to the correct
// side of the barrier (guide rule 18).
// Layout (verified, 0 bank conflicts): per 64KB buf: Ah0|Ah1|Bh0|Bh1 of
// [128 rows][128 B]; 16-B granules XOR-swizzled g' = g ^ (row&7); staging
// writes tid-linear with inverse swizzle on the per-lane global source.
__global__ __launch_bounds__(512, 1) void gemm_tanh_kernel(
        const _Float16* __restrict__ A,   // [SEQ][KEFF]
        const _Float16* __restrict__ B,   // [NN][DIM]
        const float* __restrict__ bias,   // [NN]
        float* __restrict__ out) {        // [SEQ][NN] fp32
    __shared__ _Float16 lds[65536];       // 128 KB: (A 32K | B 32K) x 2 bufs

    const int tid  = threadIdx.x;
    const int lane = tid & 63;
    const int wave = tid >> 6;            // 0..7
    const int wm   = wave >> 2;           // 0..1 (M)
    const int wn   = wave & 3;            // 0..3 (N)
    const int l15  = lane & 15;
    const int lq   = lane >> 4;           // 0..3

    // XCD map (R1): each XCD owns 2 qb columns; bijective for 512 blocks.
    const int wgid = ((blockIdx.x & 7) << 6) | (blockIdx.x >> 3);
    const int qb = wgid >> 5;             // 0..15
    const int pb = wgid & 31;             // 0..31
    const int rowBase = pb << 8;
    const int colBase = qb << 8;

    // swizzled ds_read offsets (verified)
    const int sw  = l15 & 7;
    const int gk0 = ((lq)     ^ sw) << 4;
    const int gk1 = ((4 + lq) ^ sw) << 4;
    const int aOff = wm * 2048 + l15 * 128;
    const int bOff = 32768 + wn * 2048 + l15 * 128;

    // staging map (verified)
    const int srow = tid >> 3;            // 0..63
    const int sg   = (tid & 7) ^ (srow & 7);
    const unsigned ldsWave = (unsigned)wave << 10;

    const _Float16* Ag = A + (size_t)(rowBase + srow) * KEFF + sg * 8;
    const _Float16* Bg = B + (size_t)(colBase + srow) * DIM  + sg * 8;
    char* ldsc = (char*)lds;

    auto stageA = [&](int kt, int h, int d) {
        const _Float16* g = Ag + (size_t)h * 128 * KEFF + kt * 64;
        const unsigned lo = (unsigned)d * 65536u + (unsigned)h * 16384u + ldsWave;
        __builtin_amdgcn_global_load_lds((const as1_u8*)g,
                                         (as3_u8*)(ldsc + lo), 16, 0, 0);
        __builtin_amdgcn_global_load_lds((const as1_u8*)(g + (size_t)64 * KEFF),
                                         (as3_u8*)(ldsc + lo + 8192), 16, 0, 0);
    };
    auto stageB = [&](int kt, int h, int d) {
        const _Float16* g = Bg + (size_t)h * 128 * DIM + (kt & 15) * 64;
        const unsigned lo = (unsigned)d * 65536u + 32768u + (unsigned)h * 16384u + ldsWave;
        __builtin_amdgcn_global_load_lds((const as1_u8*)g,
                                         (as3_u8*)(ldsc + lo), 16, 0, 0);
        __builtin_amdgcn_global_load_lds((const as1_u8*)(g + (size_t)64 * DIM),
                                         (as3_u8*)(ldsc + lo + 8192), 16, 0, 0);
    };

    f32x4 acc[8][4] = {};
    f16x8 aH0[4][2], aH1[4][2], bN01[2][2], bN23[2][2];

    // Prologue: stage KT0 -> buf0; publish; pre-read q00 frags.
    stageA(0, 0, 0); stageA(0, 1, 0); stageB(0, 0, 0); stageB(0, 1, 0);
    asm volatile("s_waitcnt vmcnt(0)" ::: "memory");
    __builtin_amdgcn_sched_barrier(0);
    __builtin_amdgcn_s_barrier();
    __builtin_amdgcn_sched_barrier(0);
#pragma unroll
    for (int i = 0; i < 4; ++i) {
        aH0[i][0] = *(const f16x8*)(ldsc + aOff + i * 4096 + gk0);
        aH0[i][1] = *(const f16x8*)(ldsc + aOff + i * 4096 + gk1);
    }
#pragma unroll
    for (int j = 0; j < 2; ++j) {
        bN01[j][0] = *(const f16x8*)(ldsc + bOff + j * 8192 + gk0);
        bN01[j][1] = *(const f16x8*)(ldsc + bOff + j * 8192 + gk1);
    }

    for (int t = 0; t < NT; ++t) {
        const int d  = t & 1;
        const int dn = d ^ 1;
        const char* lb  = ldsc + d * 65536;
        const char* lbn = ldsc + dn * 65536;

        // ---- top: stage KT(t+1) -> dn (8 gload_lds, in flight till mid)
        if (t + 1 < NT) {
            stageA(t + 1, 0, dn); stageA(t + 1, 1, dn);
            stageB(t + 1, 0, dn); stageB(t + 1, 1, dn);
        }

        // ---- q00: MFMA(aH0 x bN01) || read bN23(d)
#pragma unroll
        for (int j = 0; j < 2; ++j) {
            bN23[j][0] = *(const f16x8*)(lb + bOff + 16384 + j * 8192 + gk0);
            bN23[j][1] = *(const f16x8*)(lb + bOff + 16384 + j * 8192 + gk1);
        }
        __builtin_amdgcn_s_setprio(1);
#pragma unroll
        for (int k = 0; k < 2; ++k)
#pragma unroll
            for (int i = 0; i < 4; ++i)
#pragma unroll
                for (int j = 0; j < 2; ++j)
                    acc[i][j] = __builtin_amdgcn_mfma_f32_16x16x32_f16(
                        aH0[i][k], bN01[j][k], acc[i][j], 0, 0, 0);
        __builtin_amdgcn_s_setprio(0);

        // ---- q01: MFMA(aH0 x bN23) || read aH1(d)
#pragma unroll
        for (int i = 0; i < 4; ++i) {
            aH1[i][0] = *(const f16x8*)(lb + aOff + 16384 + i * 4096 + gk0);
            aH1[i][1] = *(const f16x8*)(lb + aOff + 16384 + i * 4096 + gk1);
        }
        __builtin_amdgcn_s_setprio(1);
#pragma unroll
        for (int k = 0; k < 2; ++k)
#pragma unroll
            for (int i = 0; i < 4; ++i)
#pragma unroll
                for (int j = 0; j < 2; ++j)
                    acc[i][2 + j] = __builtin_amdgcn_mfma_f32_16x16x32_f16(
                        aH0[i][k], bN23[j][k], acc[i][2 + j], 0, 0, 0);
        __builtin_amdgcn_s_setprio(0);

        // ---- mid: drain own d-reads; staging landed; publish dn / free d
        asm volatile("s_waitcnt lgkmcnt(0)" ::: "memory");
        __builtin_amdgcn_sched_barrier(0);
        asm volatile("s_waitcnt vmcnt(0)" ::: "memory");
        __builtin_amdgcn_sched_barrier(0);
        __builtin_amdgcn_s_barrier();
        __builtin_amdgcn_sched_barrier(0);

        // ---- q10: MFMA(aH1 x bN01) || read aH0'(dn) for KT(t+1)
        if (t + 1 < NT) {
#pragma unroll
            for (int i = 0; i < 4; ++i) {
                aH0[i][0] = *(const f16x8*)(lbn + aOff + i * 4096 + gk0);
                aH0[i][1] = *(const f16x8*)(lbn + aOff + i * 4096 + gk1);
            }
        }
        __builtin_amdgcn_s_setprio(1);
#pragma unroll
        for (int k = 0; k < 2; ++k)
#pragma unroll
            for (int i = 0; i < 4; ++i)
#pragma unroll
                for (int j = 0; j < 2; ++j)
                    acc[4 + i][j] = __builtin_amdgcn_mfma_f32_16x16x32_f16(
                        aH1[i][k], bN01[j][k], acc[4 + i][j], 0, 0, 0);
        __builtin_amdgcn_s_setprio(0);

        // ---- q11: MFMA(aH1 x bN23) || read bN01'(dn) for KT(t+1)
        if (t + 1 < NT) {
#pragma unroll
            for (int j = 0; j < 2; ++j) {
                bN01[j][0] = *(const f16x8*)(lbn + bOff + j * 8192 + gk0);
                bN01[j][1] = *(const f16x8*)(lbn + bOff + j * 8192 + gk1);
            }
        }
        __builtin_amdgcn_s_setprio(1);
#pragma unroll
        for (int k = 0; k < 2; ++k)
#pragma unroll
            for (int i = 0; i < 4; ++i)
#pragma unroll
                for (int j = 0; j < 2; ++j)
                    acc[4 + i][2 + j] = __builtin_amdgcn_mfma_f32_16x16x32_f16(
                        aH1[i][k], bN23[j][k], acc[4 + i][2 + j], 0, 0, 0);
        __builtin_amdgcn_s_setprio(0);
    }

    // Epilogue (verified): C/D col = lane&15, row = (lane>>4)*4 + reg.
#pragma unroll
    for (int j = 0; j < 4; ++j) {
        const int col = colBase + (j * 4 + wn) * 16 + l15;
        const float bj = bias[col];
#pragma unroll
        for (int r = 0; r < 8; ++r) {
            const size_t rb = (size_t)(rowBase + (r * 2 + wm) * 16 + lq * 4) * NN + col;
#pragma unroll
            for (int v = 0; v < 4; ++v)
                out[rb + (size_t)v * NN] = fast_tanh(acc[r][j][v] + bj);
        }
    }
}

// ---------------------------------------------------------------------------
// Fallback (only if workspace too small): naive fp32 tiled GEMM.
__global__ void naive_gemm_kernel(const float* __restrict__ x,
                                  const float* __restrict__ W,
                                  const float* __restrict__ b,
                                  float* __restrict__ out) {
    __shared__ float xs[16][17], ws[16][17];
    int n = blockIdx.x * 16 + threadIdx.x;
    int m = blockIdx.y * 16 + threadIdx.y;
    float s = 0.f;
    for (int k0 = 0; k0 < DIM; k0 += 16) {
        xs[threadIdx.y][threadIdx.x] = x[(size_t)m * DIM + k0 + threadIdx.x];
        ws[threadIdx.y][threadIdx.x] =
            W[(size_t)(blockIdx.x * 16 + threadIdx.y) * DIM + k0 + threadIdx.x];
        __syncthreads();
#pragma unroll
        for (int kk = 0; kk < 16; kk++) s += xs[threadIdx.y][kk] * ws[threadIdx.x][kk];
        __syncthreads();
    }
    out[(size_t)m * NN + n] = tanhf(s + b[n]);
}

// ---------------------------------------------------------------------------
extern "C" void kernel_launch(void* const* d_in, const int* in_sizes, int n_in,
                              void* d_out, int out_size, void* d_ws, size_t ws_size,
                              hipStream_t stream) {
    const float* x = (const float*)d_in[0];
    const float* W = (const float*)d_in[1];
    const float* b = (const float*)d_in[2];
    float* out = (float*)d_out;

    const size_t need = A_BYTES + B_BYTES;   // 41.94 MB
    if (ws_size < need) {
        dim3 grid(NN / 16, SEQ / 16), block(16, 16);
        naive_gemm_kernel<<<grid, block, 0, stream>>>(x, W, b, out);
        return;
    }

    _Float16* Abuf = (_Float16*)d_ws;
    _Float16* Bbuf = Abuf + (size_t)SEQ * KEFF;

    convert_kernel<<<12288, 256, 0, stream>>>(x, W, (f16x4*)Abuf, (f16x4*)Bbuf);

    gemm_tanh_kernel<<<512, 512, 0, stream>>>(Abuf, Bbuf, b, out);
}